// Round 4
// baseline (67.319 us; speedup 1.0000x reference)
//
#include <hip/hip_runtime.h>

#define GROUPS 64
#define DIMS 8
#define ACCW 10      // 8 sums + ssq + count
#define LSTRIDE 11   // LDS int stride (break pow2 bank pattern)
#define BPI 256      // blocks per image (2048 blocks -> 8 blocks/CU -> 32 waves/CU)
#define BLK 256      // 4 waves/block, one LDS acc copy per wave (proven core)
#define NIMG 8
#define SCALE 262144.0f          // 2^18
#define INV_SCALE (1.0f / 262144.0f)

__global__ __launch_bounds__(BLK) void k_accum(const float* __restrict__ pred,
                                               const int* __restrict__ gt,
                                               unsigned long long* __restrict__ gacc,
                                               unsigned long long* __restrict__ ticket,
                                               float* __restrict__ out,
                                               int N) {
    // acc (11264 B) and the finisher's means table (18432 B) never live at the
    // same time -> union them so LDS/block = 18.5 KB and 8 blocks/CU fit.
    __shared__ __align__(16) char ldsbuf[NIMG * GROUPS * (DIMS + 1) * 4];  // 18432 B
    __shared__ float lossArr[NIMG];
    __shared__ int isLast;
    int (*acc)[GROUPS * LSTRIDE] = (int (*)[GROUPS * LSTRIDE])ldsbuf;

    const int tid = threadIdx.x;
    const int wave = tid >> 6;
    const int b = blockIdx.y;
    for (int i = tid; i < 4 * GROUPS * LSTRIDE; i += BLK) ((int*)acc)[i] = 0;
    __syncthreads();

    const float4* pb = (const float4*)(pred + (size_t)b * N * DIMS);
    const int* gb = gt + (size_t)b * N;
    for (int idx = blockIdx.x * BLK + tid; idx < N; idx += BPI * BLK) {
        int g = gb[idx];
        float4 p0 = pb[2 * idx];
        float4 p1 = pb[2 * idx + 1];
        int* a = &acc[wave][g * LSTRIDE];
        atomicAdd(a + 0, __float2int_rn(p0.x * SCALE));
        atomicAdd(a + 1, __float2int_rn(p0.y * SCALE));
        atomicAdd(a + 2, __float2int_rn(p0.z * SCALE));
        atomicAdd(a + 3, __float2int_rn(p0.w * SCALE));
        atomicAdd(a + 4, __float2int_rn(p1.x * SCALE));
        atomicAdd(a + 5, __float2int_rn(p1.y * SCALE));
        atomicAdd(a + 6, __float2int_rn(p1.z * SCALE));
        atomicAdd(a + 7, __float2int_rn(p1.w * SCALE));
        float ssq = p0.x*p0.x + p0.y*p0.y + p0.z*p0.z + p0.w*p0.w
                  + p1.x*p1.x + p1.y*p1.y + p1.z*p1.z + p1.w*p1.w;
        atomicAdd(a + 8, __float2int_rn(ssq * SCALE));
        atomicAdd(a + 9, 1);
    }
    __syncthreads();

    for (int i = tid; i < GROUPS * ACCW; i += BLK) {
        int g = i / ACCW, k = i % ACCW;
        long long v = (long long)acc[0][g * LSTRIDE + k]
                    + (long long)acc[1][g * LSTRIDE + k]
                    + (long long)acc[2][g * LSTRIDE + k]
                    + (long long)acc[3][g * LSTRIDE + k];
        atomicAdd(&gacc[(b * GROUPS + g) * ACCW + k], (unsigned long long)v);
    }

    // __syncthreads drains vmcnt(0) per wave, so this block's device-scope gacc
    // atomics are complete at the coherent point before the ticket RMW below.
    // RELAXED scope-agent RMW: no L2 writeback/invalidate (the acq_rel flush
    // storm was the round-1/2 regression).
    __syncthreads();
    if (tid == 0) {
        unsigned long long t = __hip_atomic_fetch_add(ticket, 1ull, __ATOMIC_RELAXED,
                                                      __HIP_MEMORY_SCOPE_AGENT);
        isLast = (t == (unsigned long long)(BPI * NIMG) - 1ull) ? 1 : 0;
    }
    __syncthreads();
    if (!isLast) return;

    // ---------- finisher: runs once in the last block (verified in rounds 2/3) ----------
    float (*smf)[DIMS + 1] = (float (*)[DIMS + 1])ldsbuf;   // [NIMG*GROUPS][9]
    const int wv = tid >> 6;
    const int g = tid & 63;
    for (int ib = wv; ib < NIMG; ib += 4) {            // each of 4 waves handles 2 images
        unsigned long long ga[ACCW];
        const unsigned long long* gp = gacc + (ib * GROUPS + g) * ACCW;
        for (int k = 0; k < ACCW; ++k)
            ga[k] = __hip_atomic_load(gp + k, __ATOMIC_RELAXED, __HIP_MEMORY_SCOPE_AGENT);
        float c = (float)(long long)ga[9];
        float ssq = (float)(long long)ga[8] * INV_SCALE;
        float safe = fmaxf(c, 1.f);
        float m[DIMS];
        float msq = 0.f;
        float* row = smf[ib * GROUPS + g];
        for (int d = 0; d < DIMS; ++d) {
            m[d] = ((float)(long long)ga[d] * INV_SCALE) / safe;
            row[d] = m[d];
            msq += m[d] * m[d];
        }
        bool present = c > 0.f;
        row[DIMS] = present ? 1.f : 0.f;

        float sumsq = ssq - c * msq;
        float pull_g = present ? sumsq / (safe * (float)DIMS) : 0.f;

        unsigned long long mask = __ballot(present);
        float num = (float)__popcll(mask);

        float pull = pull_g;
        for (int off = 32; off; off >>= 1) pull += __shfl_xor(pull, off);

        // push: reads only this image's rows, all written by this same wave
        // (lockstep, in-order DS pipe) -- no barrier needed (verified r2/r3).
        float pg = 0.f;
        if (present) {
            for (int j = 0; j < GROUPS; ++j) {
                const float* rj = smf[ib * GROUPS + j];
                float pm = rj[DIMS];
                float d2 = 0.f;
                for (int d = 0; d < DIMS; ++d) {
                    float t2 = m[d] - rj[d];
                    d2 += t2 * t2;
                }
                pg += pm * expf(-d2);
            }
        }
        for (int off = 32; off; off >>= 1) pg += __shfl_xor(pg, off);

        if (g == 0) {
            float push = (pg - num) / ((num - 1.f) * num + 1e-6f) * 0.5f;
            lossArr[ib] = push + pull / (num + 1e-6f);
        }
    }
    __syncthreads();
    if (tid == 0) {
        float s = 0.f;
        for (int i = 0; i < NIMG; ++i) s += lossArr[i];
        out[0] = s * (1.f / (float)NIMG);
    }
}

extern "C" void kernel_launch(void* const* d_in, const int* in_sizes, int n_in,
                              void* d_out, int out_size, void* d_ws, size_t ws_size,
                              hipStream_t stream) {
    const float* pred = (const float*)d_in[0];
    const int* gt = (const int*)d_in[1];
    const int N = in_sizes[1] / NIMG;   // 500000

    unsigned long long* gacc = (unsigned long long*)d_ws;      // [NIMG][GROUPS][ACCW]
    unsigned long long* ticket = gacc + NIMG * GROUPS * ACCW;  // 1 word after

    hipMemsetAsync(d_ws, 0, (NIMG * GROUPS * ACCW + 1) * sizeof(unsigned long long), stream);

    dim3 grid(BPI, NIMG);
    k_accum<<<grid, BLK, 0, stream>>>(pred, gt, gacc, ticket, (float*)d_out, N);
}